// Round 1
// baseline (340.034 us; speedup 1.0000x reference)
//
#include <hip/hip_runtime.h>

#define H 64
#define NPIX 65536
#define LBATCH 8
#define LC 24
#define S_CHUNKS 128
#define PB 512             // pixels per block (3072 blocks = 12/CU = 3 clean rounds at residency 4)
#define EPSF 1e-6f
#define LN2_50 34.6573590f // 50 * ln(2): U50 = 50*(ln a - ln b) = LN2_50*(log2 a - log2 b)

typedef _Float16 h8 __attribute__((ext_vector_type(8)));   // MFMA operand view
typedef __fp16   g2 __attribute__((ext_vector_type(2)));   // cvt_pkrtz result view
typedef float f32x16 __attribute__((ext_vector_type(16)));
union H8u { h8 v8; g2 v2[4]; };                            // layout-identical pun

// inverse-quadratic RBF eval on pre-scaled coords: 1/(1+d^2)
#define KEV(d) __builtin_amdgcn_rcpf(fmaf((d), (d), 1.0f))
#define PK(a, b) __builtin_amdgcn_cvt_pkrtz((a), (b))

__global__ __launch_bounds__(256) void hist_zero(float* __restrict__ out,
                                                 float* __restrict__ ws) {
    out[blockIdx.x * 256 + threadIdx.x] = 0.0f;
    if (blockIdx.x == 0 && threadIdx.x < LBATCH) ws[threadIdx.x] = 0.0f;
}

// One block per (lc, 512-pixel chunk). Phase 1: stage U50/V50/w into LDS.
// Phase 2: each of 4 waves MFMA-accumulates the full 64x64 over its 128-pixel
// slice (8 K-steps). Merge via LDS atomics, then global atomics + a fused
// per-sample total (wave-reduced into ws[l]) so the finish pass is a pure scale.
__global__ __launch_bounds__(256, 4) void hist_main(const float* __restrict__ x,
                                                    float* __restrict__ out,
                                                    float* __restrict__ ws) {
    __shared__ float sU[PB];
    __shared__ float sV[PB];
    __shared__ float sW[PB];
    __shared__ float sHist[H * H];

    const int tid  = threadIdx.x;
    const int wv   = tid >> 6;
    const int lane = tid & 63;
    const int hf   = lane >> 5;
    const int ln   = lane & 31;
    const int lc   = blockIdx.y;
    const int l    = lc / 3;
    const int c    = lc - 3 * l;

    // zero block histogram (float4 stores)
    #pragma unroll
    for (int r = 0; r < 4; r++)
        *(float4*)&sHist[(r * 256 + tid) * 4] = make_float4(0.f, 0.f, 0.f, 0.f);

    const float* __restrict__ x0p = x + (l * 3 + 0) * NPIX;
    const float* __restrict__ x1p = x + (l * 3 + 1) * NPIX;
    const float* __restrict__ x2p = x + (l * 3 + 2) * NPIX;
    const int base = blockIdx.x * PB;

    // ---- Phase 1: cooperative pixel prep (2 px/thread) ----
    {
        const int ploc = tid * 2;
        const float2 r0 = *(const float2*)&x0p[base + ploc];
        const float2 r1 = *(const float2*)&x1p[base + ploc];
        const float2 r2 = *(const float2*)&x2p[base + ploc];
        float2 U2, V2, W2;
        #define PREP(E) { \
            const float v0 = fminf(fmaxf(r0.E, 0.0f), 1.0f); \
            const float v1 = fminf(fmaxf(r1.E, 0.0f), 1.0f); \
            const float v2 = fminf(fmaxf(r2.E, 0.0f), 1.0f); \
            W2.E = __builtin_amdgcn_sqrtf(fmaf(v0, v0, fmaf(v1, v1, fmaf(v2, v2, EPSF)))); \
            const float lg0 = __builtin_amdgcn_logf(v0 + EPSF); \
            const float lg1 = __builtin_amdgcn_logf(v1 + EPSF); \
            const float lg2 = __builtin_amdgcn_logf(v2 + EPSF); \
            float U, V; \
            if (c == 0)      { U = lg0 - lg1; V = lg0 - lg2; } \
            else if (c == 1) { U = lg1 - lg0; V = lg1 - lg2; } \
            else             { U = lg2 - lg0; V = lg2 - lg1; } \
            U2.E = LN2_50 * U; V2.E = LN2_50 * V; }
        PREP(x) PREP(y)
        #undef PREP
        *(float2*)&sU[ploc] = U2;
        *(float2*)&sV[ploc] = V2;
        *(float2*)&sW[ploc] = W2;
    }
    __syncthreads();

    // ---- Phase 2: MFMA K-loop over this wave's 128-pixel slice ----
    const float step50 = 50.0f * (6.0f / 63.0f);
    const float ou0 = -150.0f + step50 * (float)ln;  // u/v bins [0,32)
    const float ou1 = ou0 + step50 * 32.0f;          // u/v bins [32,64)

    f32x16 acc00, acc01, acc10, acc11;
    #pragma unroll
    for (int i = 0; i < 16; i++) { acc00[i] = 0.f; acc01[i] = 0.f; acc10[i] = 0.f; acc11[i] = 0.f; }

    const int wbase = wv * 128;
    #pragma unroll 2
    for (int ks = 0; ks < 8; ks++) {
        const int kb = wbase + ks * 16 + hf * 8;     // half-wave's 8 k-pixels
        const float4 ua = *(const float4*)&sU[kb];
        const float4 ub = *(const float4*)&sU[kb + 4];
        const float4 va = *(const float4*)&sV[kb];
        const float4 vb = *(const float4*)&sV[kb + 4];
        const float4 wa = *(const float4*)&sW[kb];
        const float4 wb = *(const float4*)&sW[kb + 4];
        H8u A0, A1, B0, B1;
        A0.v2[0] = PK(wa.x * KEV(ua.x - ou0), wa.y * KEV(ua.y - ou0));
        A0.v2[1] = PK(wa.z * KEV(ua.z - ou0), wa.w * KEV(ua.w - ou0));
        A0.v2[2] = PK(wb.x * KEV(ub.x - ou0), wb.y * KEV(ub.y - ou0));
        A0.v2[3] = PK(wb.z * KEV(ub.z - ou0), wb.w * KEV(ub.w - ou0));
        A1.v2[0] = PK(wa.x * KEV(ua.x - ou1), wa.y * KEV(ua.y - ou1));
        A1.v2[1] = PK(wa.z * KEV(ua.z - ou1), wa.w * KEV(ua.w - ou1));
        A1.v2[2] = PK(wb.x * KEV(ub.x - ou1), wb.y * KEV(ub.y - ou1));
        A1.v2[3] = PK(wb.z * KEV(ub.z - ou1), wb.w * KEV(ub.w - ou1));
        B0.v2[0] = PK(KEV(va.x - ou0), KEV(va.y - ou0));
        B0.v2[1] = PK(KEV(va.z - ou0), KEV(va.w - ou0));
        B0.v2[2] = PK(KEV(vb.x - ou0), KEV(vb.y - ou0));
        B0.v2[3] = PK(KEV(vb.z - ou0), KEV(vb.w - ou0));
        B1.v2[0] = PK(KEV(va.x - ou1), KEV(va.y - ou1));
        B1.v2[1] = PK(KEV(va.z - ou1), KEV(va.w - ou1));
        B1.v2[2] = PK(KEV(vb.x - ou1), KEV(vb.w - ou1));
        B1.v2[3] = PK(KEV(vb.z - ou1), KEV(vb.w - ou1));
        // NOTE: the two lines above must use vb.z/vb.w correctly; fixed below.
        B1.v2[2] = PK(KEV(vb.x - ou1), KEV(vb.y - ou1));
        B1.v2[3] = PK(KEV(vb.z - ou1), KEV(vb.w - ou1));
        acc00 = __builtin_amdgcn_mfma_f32_32x32x16_f16(A0.v8, B0.v8, acc00, 0, 0, 0);
        acc01 = __builtin_amdgcn_mfma_f32_32x32x16_f16(A0.v8, B1.v8, acc01, 0, 0, 0);
        acc10 = __builtin_amdgcn_mfma_f32_32x32x16_f16(A1.v8, B0.v8, acc10, 0, 0, 0);
        acc11 = __builtin_amdgcn_mfma_f32_32x32x16_f16(A1.v8, B1.v8, acc11, 0, 0, 0);
    }

    // merge 4 wave accumulators (C/D layout: col=ln, row=(r&3)+8*(r>>2)+4*hf)
    #pragma unroll
    for (int r = 0; r < 16; r++) {
        const int row = (r & 3) + 8 * (r >> 2) + 4 * hf;
        atomicAdd(&sHist[row * 64 + ln],             acc00[r]);
        atomicAdd(&sHist[row * 64 + 32 + ln],        acc01[r]);
        atomicAdd(&sHist[(row + 32) * 64 + ln],      acc10[r]);
        atomicAdd(&sHist[(row + 32) * 64 + 32 + ln], acc11[r]);
    }
    __syncthreads();

    // global merge + fused per-sample total (for the scale pass)
    float* __restrict__ g = out + lc * (H * H);
    float s = 0.0f;
    #pragma unroll
    for (int r = 0; r < 16; r++) {
        const int i = r * 256 + tid;
        const float v = sHist[i];
        s += v;
        unsafeAtomicAdd(&g[i], v);
    }
    #pragma unroll
    for (int off = 32; off > 0; off >>= 1) s += __shfl_down(s, off, 64);
    if (lane == 0) unsafeAtomicAdd(&ws[l], s);
}

// pure scale pass: fully parallel (96 blocks), total comes from ws
__global__ __launch_bounds__(256) void hist_scale(float* __restrict__ out,
                                                  const float* __restrict__ ws) {
    const int i4 = blockIdx.x * 256 + threadIdx.x;   // float4 index
    const int l  = blockIdx.x / 12;                  // 12 blocks per sample (3*4096/1024)
    const float inv = 1.0f / (ws[l] + EPSF);
    float4 v = *(const float4*)&out[i4 * 4];
    v.x *= inv; v.y *= inv; v.z *= inv; v.w *= inv;
    *(float4*)&out[i4 * 4] = v;
}

extern "C" void kernel_launch(void* const* d_in, const int* in_sizes, int n_in,
                              void* d_out, int out_size, void* d_ws, size_t ws_size,
                              hipStream_t stream) {
    const float* x = (const float*)d_in[0];
    float* out = (float*)d_out;
    float* ws = (float*)d_ws;

    hipLaunchKernelGGL(hist_zero,  dim3(LC * H * H / 256),      dim3(256), 0, stream, out, ws);
    hipLaunchKernelGGL(hist_main,  dim3(S_CHUNKS, LC),          dim3(256), 0, stream, x, out, ws);
    hipLaunchKernelGGL(hist_scale, dim3(LBATCH * 3 * H * H / 1024), dim3(256), 0, stream, out, ws);
}

// Round 2
// 153.612 us; speedup vs baseline: 2.2136x; 2.2136x over previous
//
#include <hip/hip_runtime.h>

#define H 64
#define NPIX 65536
#define LBATCH 8
#define LC 24
#define S_CHUNKS 32
#define PB 2048            // pixels per block
#define EPSF 1e-6f
#define LN2_50 34.6573590f // 50 * ln(2): U50 = 50*(ln a - ln b) = LN2_50*(log2 a - log2 b)
#define NPART (LC * S_CHUNKS)        // 768 partial histograms
#define PART_FLOATS (NPART * H * H)  // 3,145,728 floats = 12.58 MB of d_ws

typedef _Float16 h8 __attribute__((ext_vector_type(8)));   // MFMA operand view
typedef __fp16   g2 __attribute__((ext_vector_type(2)));   // cvt_pkrtz result view
typedef float f32x16 __attribute__((ext_vector_type(16)));
union H8u { h8 v8; g2 v2[4]; };                            // layout-identical pun

// inverse-quadratic RBF eval on pre-scaled coords: 1/(1+d^2)
#define KEV(d) __builtin_amdgcn_rcpf(fmaf((d), (d), 1.0f))
#define PK(a, b) __builtin_amdgcn_cvt_pkrtz((a), (b))

// One block per (lc, 2048-pixel chunk). Phase 1: stage U50/V50/w into LDS.
// Phase 2: each of 4 waves MFMA-accumulates the full 64x64 over its 512-pixel
// slice. Merge 4 waves via LDS atomics, then flush the 16KB partial histogram
// to a PRIVATE d_ws slice with plain streaming float4 stores — NO global
// atomics (prior versions were bound at ~185 GB/s memory-side atomic RMW).
__global__ __launch_bounds__(256, 3) void hist_main(const float* __restrict__ x,
                                                    float* __restrict__ ws) {
    __shared__ float sU[PB];
    __shared__ float sV[PB];
    __shared__ float sW[PB];
    __shared__ float sHist[H * H];

    const int tid  = threadIdx.x;
    const int wv   = tid >> 6;
    const int lane = tid & 63;
    const int hf   = lane >> 5;
    const int ln   = lane & 31;
    const int lc   = blockIdx.y;
    const int l    = lc / 3;
    const int c    = lc - 3 * l;

    // zero block histogram (float4 stores)
    #pragma unroll
    for (int r = 0; r < 4; r++)
        *(float4*)&sHist[(r * 256 + tid) * 4] = make_float4(0.f, 0.f, 0.f, 0.f);

    const float* __restrict__ x0p = x + (l * 3 + 0) * NPIX;
    const float* __restrict__ x1p = x + (l * 3 + 1) * NPIX;
    const float* __restrict__ x2p = x + (l * 3 + 2) * NPIX;
    const int base = blockIdx.x * PB;

    // ---- Phase 1: cooperative pixel prep (2 passes x 4 px/thread) ----
    #pragma unroll
    for (int pass = 0; pass < 2; pass++) {
        const int ploc = pass * 1024 + tid * 4;
        const float4 r0 = *(const float4*)&x0p[base + ploc];
        const float4 r1 = *(const float4*)&x1p[base + ploc];
        const float4 r2 = *(const float4*)&x2p[base + ploc];
        float4 U4, V4, W4;
        #define PREP(E) { \
            const float v0 = fminf(fmaxf(r0.E, 0.0f), 1.0f); \
            const float v1 = fminf(fmaxf(r1.E, 0.0f), 1.0f); \
            const float v2 = fminf(fmaxf(r2.E, 0.0f), 1.0f); \
            W4.E = __builtin_amdgcn_sqrtf(fmaf(v0, v0, fmaf(v1, v1, fmaf(v2, v2, EPSF)))); \
            const float lg0 = __builtin_amdgcn_logf(v0 + EPSF); \
            const float lg1 = __builtin_amdgcn_logf(v1 + EPSF); \
            const float lg2 = __builtin_amdgcn_logf(v2 + EPSF); \
            float U, V; \
            if (c == 0)      { U = lg0 - lg1; V = lg0 - lg2; } \
            else if (c == 1) { U = lg1 - lg0; V = lg1 - lg2; } \
            else             { U = lg2 - lg0; V = lg2 - lg1; } \
            U4.E = LN2_50 * U; V4.E = LN2_50 * V; }
        PREP(x) PREP(y) PREP(z) PREP(w)
        #undef PREP
        *(float4*)&sU[ploc] = U4;
        *(float4*)&sV[ploc] = V4;
        *(float4*)&sW[ploc] = W4;
    }
    __syncthreads();

    // ---- Phase 2: MFMA K-loop over this wave's 512-pixel slice ----
    const float step50 = 50.0f * (6.0f / 63.0f);
    const float ou0 = -150.0f + step50 * (float)ln;  // u/v bins [0,32)
    const float ou1 = ou0 + step50 * 32.0f;          // u/v bins [32,64)

    f32x16 acc00, acc01, acc10, acc11;
    #pragma unroll
    for (int i = 0; i < 16; i++) { acc00[i] = 0.f; acc01[i] = 0.f; acc10[i] = 0.f; acc11[i] = 0.f; }

    const int wbase = wv * 512;
    #pragma unroll 2
    for (int ks = 0; ks < 32; ks++) {
        const int kb = wbase + ks * 16 + hf * 8;     // half-wave's 8 k-pixels
        const float4 ua = *(const float4*)&sU[kb];
        const float4 ub = *(const float4*)&sU[kb + 4];
        const float4 va = *(const float4*)&sV[kb];
        const float4 vb = *(const float4*)&sV[kb + 4];
        const float4 wa = *(const float4*)&sW[kb];
        const float4 wb = *(const float4*)&sW[kb + 4];
        H8u A0, A1, B0, B1;
        A0.v2[0] = PK(wa.x * KEV(ua.x - ou0), wa.y * KEV(ua.y - ou0));
        A0.v2[1] = PK(wa.z * KEV(ua.z - ou0), wa.w * KEV(ua.w - ou0));
        A0.v2[2] = PK(wb.x * KEV(ub.x - ou0), wb.y * KEV(ub.y - ou0));
        A0.v2[3] = PK(wb.z * KEV(ub.z - ou0), wb.w * KEV(ub.w - ou0));
        A1.v2[0] = PK(wa.x * KEV(ua.x - ou1), wa.y * KEV(ua.y - ou1));
        A1.v2[1] = PK(wa.z * KEV(ua.z - ou1), wa.w * KEV(ua.w - ou1));
        A1.v2[2] = PK(wb.x * KEV(ub.x - ou1), wb.y * KEV(ub.y - ou1));
        A1.v2[3] = PK(wb.z * KEV(ub.z - ou1), wb.w * KEV(ub.w - ou1));
        B0.v2[0] = PK(KEV(va.x - ou0), KEV(va.y - ou0));
        B0.v2[1] = PK(KEV(va.z - ou0), KEV(va.w - ou0));
        B0.v2[2] = PK(KEV(vb.x - ou0), KEV(vb.y - ou0));
        B0.v2[3] = PK(KEV(vb.z - ou0), KEV(vb.w - ou0));
        B1.v2[0] = PK(KEV(va.x - ou1), KEV(va.y - ou1));
        B1.v2[1] = PK(KEV(va.z - ou1), KEV(va.w - ou1));
        B1.v2[2] = PK(KEV(vb.x - ou1), KEV(vb.y - ou1));
        B1.v2[3] = PK(KEV(vb.z - ou1), KEV(vb.w - ou1));
        acc00 = __builtin_amdgcn_mfma_f32_32x32x16_f16(A0.v8, B0.v8, acc00, 0, 0, 0);
        acc01 = __builtin_amdgcn_mfma_f32_32x32x16_f16(A0.v8, B1.v8, acc01, 0, 0, 0);
        acc10 = __builtin_amdgcn_mfma_f32_32x32x16_f16(A1.v8, B0.v8, acc10, 0, 0, 0);
        acc11 = __builtin_amdgcn_mfma_f32_32x32x16_f16(A1.v8, B1.v8, acc11, 0, 0, 0);
    }

    // merge 4 wave accumulators (C/D layout: col=ln, row=(r&3)+8*(r>>2)+4*hf)
    #pragma unroll
    for (int r = 0; r < 16; r++) {
        const int row = (r & 3) + 8 * (r >> 2) + 4 * hf;
        atomicAdd(&sHist[row * 64 + ln],             acc00[r]);
        atomicAdd(&sHist[row * 64 + 32 + ln],        acc01[r]);
        atomicAdd(&sHist[(row + 32) * 64 + ln],      acc10[r]);
        atomicAdd(&sHist[(row + 32) * 64 + 32 + ln], acc11[r]);
    }
    __syncthreads();

    // flush partial histogram to private ws slice — plain streaming stores
    float* __restrict__ g = ws + (lc * S_CHUNKS + blockIdx.x) * (H * H);
    #pragma unroll
    for (int r = 0; r < 4; r++) {
        const int i = (r * 256 + tid) * 4;
        *(float4*)&g[i] = *(const float4*)&sHist[i];
    }
}

// 96 blocks: one per (lc, quarter). Sum 32 chunk-partials, write out,
// emit per-block mass partial to wsq (plain store — no atomics, no zeroing).
__global__ __launch_bounds__(256) void hist_reduce(const float* __restrict__ ws,
                                                   float* __restrict__ out,
                                                   float* __restrict__ wsq) {
    const int lc  = blockIdx.x >> 2;
    const int off = (blockIdx.x & 3) * 1024 + threadIdx.x * 4;
    float4 a = make_float4(0.f, 0.f, 0.f, 0.f);
    #pragma unroll 8
    for (int ch = 0; ch < S_CHUNKS; ch++) {
        const float4 v = *(const float4*)&ws[(lc * S_CHUNKS + ch) * (H * H) + off];
        a.x += v.x; a.y += v.y; a.z += v.z; a.w += v.w;
    }
    *(float4*)&out[lc * (H * H) + off] = a;

    float s = (a.x + a.y) + (a.z + a.w);
    #pragma unroll
    for (int o = 32; o > 0; o >>= 1) s += __shfl_down(s, o, 64);
    __shared__ float ps[4];
    if ((threadIdx.x & 63) == 0) ps[threadIdx.x >> 6] = s;
    __syncthreads();
    if (threadIdx.x == 0) wsq[blockIdx.x] = (ps[0] + ps[1]) + (ps[2] + ps[3]);
}

// 96 blocks: normalize. Total for sample l = sum of its 12 wsq partials.
__global__ __launch_bounds__(256) void hist_scale(float* __restrict__ out,
                                                  const float* __restrict__ wsq) {
    const int lc = blockIdx.x >> 2;
    const int l  = lc / 3;
    float T = 0.f;
    #pragma unroll
    for (int j = 0; j < 12; j++) T += wsq[l * 12 + j];
    const float inv = 1.0f / (T + EPSF);
    const int off = (blockIdx.x & 3) * 1024 + threadIdx.x * 4;
    float4 v = *(const float4*)&out[lc * (H * H) + off];
    v.x *= inv; v.y *= inv; v.z *= inv; v.w *= inv;
    *(float4*)&out[lc * (H * H) + off] = v;
}

extern "C" void kernel_launch(void* const* d_in, const int* in_sizes, int n_in,
                              void* d_out, int out_size, void* d_ws, size_t ws_size,
                              hipStream_t stream) {
    const float* x = (const float*)d_in[0];
    float* out = (float*)d_out;
    float* ws = (float*)d_ws;   // needs 12.58 MB + 384 B

    hipLaunchKernelGGL(hist_main,   dim3(S_CHUNKS, LC), dim3(256), 0, stream, x, ws);
    hipLaunchKernelGGL(hist_reduce, dim3(96),           dim3(256), 0, stream, ws, out, ws + PART_FLOATS);
    hipLaunchKernelGGL(hist_scale,  dim3(96),           dim3(256), 0, stream, out, ws + PART_FLOATS);
}